// Round 3
// baseline (342.860 us; speedup 1.0000x reference)
//
#include <hip/hip_runtime.h>

// Monarch block-diag: out[b, s*64+l] = sum_r w2[l,s,r] * sum_p x[b, r*64+p] * w1[r,l,p]
// B=8192, N=4096, blocks 64. fp32 in/out (bf16-representable inputs); bf16 MFMA compute.
//
// Prologue: w1,w2 fp32 -> bf16 into d_ws.
// Main: 512 thr (8 waves), b-tile 16, grid 512. x read ONCE into persistent bf16 A-frags.
// q processed in 2 HALVES of 32 (not 4 chunks of 16) so each store phase emits complete
// 128-B output lines (l-range 32 per phase, all 8 waves fill a line within one phase):
//   stage-1: waves split k (8 each) -> Y[16b][32q][64k] bf16 in 64 KiB swizzled LDS
//   stage-2: wave w handles l = qh*32 + w*4 .. +3, all 4 s-tiles; float4 stores (4 l packed).

typedef __bf16 bf16x8 __attribute__((ext_vector_type(8)));
typedef float  float4v __attribute__((ext_vector_type(4)));

__global__ __launch_bounds__(256)
void cvt_weights(const float* __restrict__ w1, const float* __restrict__ w2,
                 __bf16* __restrict__ wb) {
    const int i = (blockIdx.x * 256 + threadIdx.x) * 8;  // grid 128 -> i < 262144
    float4v a = *(const float4v*)(w1 + i);
    float4v b = *(const float4v*)(w1 + i + 4);
    bf16x8 v;
    v[0]=(__bf16)a[0]; v[1]=(__bf16)a[1]; v[2]=(__bf16)a[2]; v[3]=(__bf16)a[3];
    v[4]=(__bf16)b[0]; v[5]=(__bf16)b[1]; v[6]=(__bf16)b[2]; v[7]=(__bf16)b[3];
    *(bf16x8*)(wb + i) = v;
    a = *(const float4v*)(w2 + i);
    b = *(const float4v*)(w2 + i + 4);
    v[0]=(__bf16)a[0]; v[1]=(__bf16)a[1]; v[2]=(__bf16)a[2]; v[3]=(__bf16)a[3];
    v[4]=(__bf16)b[0]; v[5]=(__bf16)b[1]; v[6]=(__bf16)b[2]; v[7]=(__bf16)b[3];
    *(bf16x8*)(wb + 262144 + i) = v;
}

__global__ __launch_bounds__(512, 2)
void monarch_fused(const float* __restrict__ x,
                   const __bf16* __restrict__ w1b,
                   const __bf16* __restrict__ w2b,
                   float* __restrict__ out)
{
    // Y layout: [b(16)][qloc(32)][kchunk(8) xor-swizzled][elem(8)] bf16 = 64 KiB
    __shared__ __align__(16) __bf16 Y[16 * 32 * 64];

    const int tid  = threadIdx.x;
    const int wid  = tid >> 6;      // 0..7
    const int lane = tid & 63;
    const int m    = lane & 15;     // MFMA: A-M / B-N / D-col index
    const int quad = lane >> 4;     // MFMA: A/B K-group, D row-group
    const int b0   = blockIdx.x * 16;

    // ---- preload x as bf16 A-frags: k = wid*8 + j, p = h*32 + quad*8 + e ----
    bf16x8 xa[8][2];
    {
        const float* xp = x + (long)(b0 + m) * 4096 + wid * 512 + quad * 8;
        #pragma unroll
        for (int j = 0; j < 8; ++j) {
            #pragma unroll
            for (int h = 0; h < 2; ++h) {
                float4v lo = *(const float4v*)(xp + j * 64 + h * 32);
                float4v hi = *(const float4v*)(xp + j * 64 + h * 32 + 4);
                bf16x8 v;
                v[0]=(__bf16)lo[0]; v[1]=(__bf16)lo[1]; v[2]=(__bf16)lo[2]; v[3]=(__bf16)lo[3];
                v[4]=(__bf16)hi[0]; v[5]=(__bf16)hi[1]; v[6]=(__bf16)hi[2]; v[7]=(__bf16)hi[3];
                xa[j][h] = v;
            }
        }
    }

    for (int qh = 0; qh < 2; ++qh) {
        if (qh) __syncthreads();  // previous half's stage-2 LDS reads complete

        // ---- stage 1: Y[b][qloc][k], qloc in [0,32); wave handles k in [wid*8, +8) ----
        #pragma unroll
        for (int qt = 0; qt < 2; ++qt) {
            float4v acc[8];
            #pragma unroll
            for (int j = 0; j < 8; ++j) {
                const int k = wid * 8 + j;
                const int q = qh * 32 + qt * 16 + m;
                const __bf16* w1p = w1b + ((k * 64 + q) * 64) + quad * 8;
                bf16x8 bb0 = *(const bf16x8*)(w1p);
                bf16x8 bb1 = *(const bf16x8*)(w1p + 32);
                float4v c = {0.f, 0.f, 0.f, 0.f};
                c = __builtin_amdgcn_mfma_f32_16x16x32_bf16(xa[j][0], bb0, c, 0, 0, 0);
                c = __builtin_amdgcn_mfma_f32_16x16x32_bf16(xa[j][1], bb1, c, 0, 0, 0);
                acc[j] = c;
            }
            // D: lane holds D[b = quad*4+reg][q = qt*16+m]; pack 8 k -> one b128 write.
            #pragma unroll
            for (int reg = 0; reg < 4; ++reg) {
                const int bl   = quad * 4 + reg;
                const int qloc = qt * 16 + m;
                const int cs   = wid ^ (qloc & 7) ^ (bl & 7);
                bf16x8 v;
                #pragma unroll
                for (int j = 0; j < 8; ++j) v[j] = (__bf16)acc[j][reg];
                *(bf16x8*)(&Y[((bl * 32 + qloc) * 8 + cs) * 8]) = v;
            }
        }
        __syncthreads();

        // ---- stage 2: wave handles l = qh*32 + wid*4 + li (li 0..3), all 4 s-tiles ----
        float4v acc2[4][4];  // [li][st]
        #pragma unroll
        for (int li = 0; li < 4; ++li)
            #pragma unroll
            for (int st = 0; st < 4; ++st) acc2[li][st] = (float4v){0.f, 0.f, 0.f, 0.f};

        #pragma unroll
        for (int h = 0; h < 2; ++h) {
            #pragma unroll
            for (int li = 0; li < 4; ++li) {
                const int qloc = wid * 4 + li;          // l local to this half
                const int l    = qh * 32 + qloc;
                const int kc   = h * 4 + quad;
                const int cs   = kc ^ (qloc & 7) ^ (m & 7);
                // A2[b = m][r = h*32 + quad*8 + e] = Y[b][qloc][r]
                bf16x8 a2 = *(const bf16x8*)(&Y[((m * 32 + qloc) * 8 + cs) * 8]);
                const __bf16* w2p = w2b + (l * 64) * 64 + h * 32 + quad * 8;
                #pragma unroll
                for (int st = 0; st < 4; ++st) {
                    bf16x8 b2 = *(const bf16x8*)(w2p + (st * 16 + m) * 64);
                    acc2[li][st] = __builtin_amdgcn_mfma_f32_16x16x32_bf16(a2, b2, acc2[li][st], 0, 0, 0);
                }
            }
        }

        // Store: lane holds out2[b = b0+quad*4+reg][l][s = st*16+m]; pack 4 l -> float4.
        // All 8 waves fill each 128-B line (l-range 32) within this phase -> L2 merges.
        #pragma unroll
        for (int st = 0; st < 4; ++st) {
            #pragma unroll
            for (int reg = 0; reg < 4; ++reg) {
                float4v v;
                #pragma unroll
                for (int li = 0; li < 4; ++li) v[li] = acc2[li][st][reg];
                float* dst = out + (long)(b0 + quad * 4 + reg) * 4096
                                 + (st * 16 + m) * 64 + qh * 32 + wid * 4;
                *(float4v*)dst = v;
            }
        }
    }
}

extern "C" void kernel_launch(void* const* d_in, const int* in_sizes, int n_in,
                              void* d_out, int out_size, void* d_ws, size_t ws_size,
                              hipStream_t stream) {
    const float* x  = (const float*)d_in[0];
    const float* w1 = (const float*)d_in[1];
    const float* w2 = (const float*)d_in[2];
    float* out = (float*)d_out;
    __bf16* wb = (__bf16*)d_ws;   // w1b at [0, 262144), w2b at [262144, 524288)

    hipLaunchKernelGGL(cvt_weights, dim3(128), dim3(256), 0, stream, w1, w2, wb);
    hipLaunchKernelGGL(monarch_fused, dim3(8192 / 16), dim3(512), 0, stream,
                       x, wb, wb + 262144, out);
}